// Round 7
// baseline (129.647 us; speedup 1.0000x reference)
//
#include <hip/hip_runtime.h>
#include <hip/hip_bf16.h>
#include <math.h>

// HIR rainfall-runoff scan — tolerance-bracketed time-chunking + exact fixup.
//
// V8 changes vs V7 (122.0 us; pass1 48.5 us, fixup ~13 us, ~60 us fixed
// harness overhead fitted across V1..V7):
//  * V7 falsified the prefetch-depth theory (distance-2 = distance-1 perf).
//    Stall is memory-subsystem THROUGHPUT: 8 lines/step/wave x 4 waves/CU,
//    identical in [b][t] and [t][b] layouts (V4~V6~V7). V5 showed extra
//    waves/SIMD contend on the same per-CU memory pipe.
//  * W 384 -> 320: bracket work and line traffic -14%. Same tolerance
//    regime as V2 (gap ~0.4 < MERGE_TOL .75, absmax 0.125, passed 4x).
//  * PIPE4 (distance-3, 4 buffers): free deepening, all batch counts are
//    multiples of 4.
//  * Store-phase c==0 guard hoisted out of the 64-iter loop.
//  * If pass1 lands >=46 us: line-service bound confirmed; next structural
//    step is cross-chunk LDS sharing (warm-up re-reads each input line ~6x).
//
// Q[b,t] (t>=1) = fluxes from carry entering step t; Q[b,0] uses the FINAL
// carry (jnp.roll wraparound) with t=0 inputs (chunk NC-1 owner writes it).

struct P {
    float INSC, SMSC, RecK, g1, lc, k1, k2, k3, c2;
    // g1=1-RecK, lc=log2(COEFF), k1=SUB/SMSC, k2=CRAK/SMSC, k3=10/SMSC,
    // c2=-SQ/SMSC*log2(e)
};

__device__ __forceinline__ P make_params(const float* pINSC, const float* pCOEFF,
                                         const float* pSQ,   const float* pSMSC,
                                         const float* pSUB,  const float* pCRAK,
                                         const float* pRecK) {
    P p;
    p.INSC      = fminf(fmaxf(pINSC[0]  * 5.0f,   0.5f),   5.0f);
    float COEFF = fminf(fmaxf(pCOEFF[0] * 400.0f, 50.0f),  400.0f);
    float SQ    = fminf(fmaxf(pSQ[0]    * 6.0f,   0.0f),   6.0f);
    p.SMSC      = fminf(fmaxf(pSMSC[0]  * 500.0f, 50.0f),  500.0f);
    float SUB   = fminf(fmaxf(pSUB[0],  0.0f), 1.0f);
    float CRAK  = fminf(fmaxf(pCRAK[0], 0.0f), 1.0f);
    p.RecK      = fminf(fmaxf(pRecK[0]  * 0.3f,   0.003f), 0.3f);
    p.g1 = 1.0f - p.RecK;
    p.lc = log2f(COEFF);
    float inv = 1.0f / p.SMSC;
    p.k1 = SUB * inv;
    p.k2 = CRAK * inv;
    p.k3 = 10.0f * inv;
    p.c2 = (-SQ * inv) * 1.44269504088896340736f;
    return p;
}

// Full step with Q. Critical sms chain: fminf -> fmaf -> exp2f -> fminf ->
// mul -> fmaf. Everything else is off-path.
__device__ __forceinline__ float step(float Prec, float PET, float& sms, float& gw, const P& p) {
    float INT  = fminf(fminf(p.INSC, PET), Prec);
    float INR  = Prec - INT;
    float POT  = PET - INT;
    float S    = fminf(sms, p.SMSC);                 // lower clamp provably slack
    float u    = fmaf(-p.k1, S, 1.0f);
    float v    = fmaf(-p.k2, S, 1.0f);
    float ETS  = fminf(POT, p.k3 * S);
    float SmE  = S - ETS;
    float e    = exp2f(fmaf(p.c2, S, p.lc));         // cap = COEFF*2^(c2*S)
    float RMO  = fminf(INR, e);
    float w    = u * RMO;                            // t2 = RMO - SRUN
    float s2   = fmaf(v, w, SmE);                    // S + SMF - ETS
    float SMF  = v * w;
    float REC  = w - SMF;
    float RECnew = REC + fmaxf(s2 - p.SMSC, 0.0f);
    float BAS  = p.RecK * gw;
    float Q    = (INR - w) + BAS;                    // IRUN + SRUN + BAS
    gw  = fmaf(p.g1, gw, RECnew);
    sms = s2;
    return Q;
}

// Warm-up / state-advance step without Q (single chain, carries gw).
__device__ __forceinline__ void stepw(float Prec, float PET, float& sms, float& gw, const P& p) {
    float INT  = fminf(fminf(p.INSC, PET), Prec);
    float INR  = Prec - INT;
    float POT  = PET - INT;
    float S    = fminf(sms, p.SMSC);
    float u    = fmaf(-p.k1, S, 1.0f);
    float v    = fmaf(-p.k2, S, 1.0f);
    float ETS  = fminf(POT, p.k3 * S);
    float SmE  = S - ETS;
    float e    = exp2f(fmaf(p.c2, S, p.lc));
    float RMO  = fminf(INR, e);
    float w    = u * RMO;
    float s2   = fmaf(v, w, SmE);
    float SMF  = v * w;
    float REC  = w - SMF;
    float RECnew = REC + fmaxf(s2 - p.SMSC, 0.0f);
    gw  = fmaf(p.g1, gw, RECnew);
    sms = s2;
}

// Dual-bracket warm-up step: hi chain carries gw; lo chain is sms-only.
// Shares INT/INR/POT between the chains.
__device__ __forceinline__ void dstep(float Prec, float PET,
                                      float& slo, float& shi, float& gw, const P& p) {
    float INT = fminf(fminf(p.INSC, PET), Prec);
    float INR = Prec - INT;
    float POT = PET - INT;
    {   // hi + gw
        float S    = fminf(shi, p.SMSC);
        float u    = fmaf(-p.k1, S, 1.0f);
        float v    = fmaf(-p.k2, S, 1.0f);
        float ETS  = fminf(POT, p.k3 * S);
        float SmE  = S - ETS;
        float e    = exp2f(fmaf(p.c2, S, p.lc));
        float RMO  = fminf(INR, e);
        float w    = u * RMO;
        float s2   = fmaf(v, w, SmE);
        float SMF  = v * w;
        float REC  = w - SMF;
        float RECnew = REC + fmaxf(s2 - p.SMSC, 0.0f);
        gw  = fmaf(p.g1, gw, RECnew);
        shi = s2;
    }
    {   // lo, sms only
        float S    = fminf(slo, p.SMSC);
        float u    = fmaf(-p.k1, S, 1.0f);
        float v    = fmaf(-p.k2, S, 1.0f);
        float ETS  = fminf(POT, p.k3 * S);
        float SmE  = S - ETS;
        float e    = exp2f(fmaf(p.c2, S, p.lc));
        float RMO  = fminf(INR, e);
        float w    = u * RMO;
        slo = fmaf(v, w, SmE);
    }
}

#define MERGE_TOL 0.75f

// ---------------------------------------------------------------------------
// 4-buffer, 4-float4-batch software pipeline (distance-3, no register copies).
// Ambient names: bp (const float4* batch base), B0..B3 (float4[4] buffers).
// Invariant: batch j lives in B[j%4]; the load for batch j+3 issues in batch
// j's slot. All call-site NB values are multiples of 4 (8..40) or 0; clamped
// tail loads only ever overwrite already-consumed buffers (verified for the
// unroll-4 schedule below).
// ---------------------------------------------------------------------------

#define LB(DST, K, NB) do { int _kn = (K) < (NB) ? (K) : (NB) - 1;              \
    _Pragma("unroll") for (int _q = 0; _q < 4; ++_q) DST[_q] = bp[4 * _kn + _q]; } while (0)

#define PIPE4(NB, CB) do { if ((NB) > 0) {                                      \
    LB(B0, 0, (NB)); LB(B1, 1, (NB)); LB(B2, 2, (NB));                          \
    for (int _j = 0; _j < (NB); _j += 4) {                                      \
        LB(B3, _j + 3, (NB)); CB(B0, _j);                                       \
        LB(B0, _j + 4, (NB)); CB(B1, _j + 1);                                   \
        LB(B1, _j + 5, (NB)); CB(B2, _j + 2);                                   \
        LB(B2, _j + 6, (NB)); CB(B3, _j + 3);                                   \
    }                                                                           \
} } while (0)

// Compute-batch macros (8 steps per batch).
#define CBW(BUF, J) do { _Pragma("unroll") for (int _m = 0; _m < 4; ++_m) {     \
    stepw(BUF[_m].x, BUF[_m].y, shi, gw, p);                                    \
    stepw(BUF[_m].z, BUF[_m].w, shi, gw, p); } } while (0)

#define CBD(BUF, J) do { _Pragma("unroll") for (int _m = 0; _m < 4; ++_m) {     \
    dstep(BUF[_m].x, BUF[_m].y, slo, shi, gw, p);                               \
    dstep(BUF[_m].z, BUF[_m].w, slo, shi, gw, p); } } while (0)

#define CBM(BUF, J) do { int _tb = 8 * (J);                                     \
    _Pragma("unroll") for (int _m = 0; _m < 4; ++_m) {                          \
    float _qa = step(BUF[_m].x, BUF[_m].y, sms, gw, p);                         \
    float _qb = step(BUF[_m].z, BUF[_m].w, sms, gw, p);                         \
    lds_q[_tb + 2 * _m][l] = _qa; lds_q[_tb + 2 * _m + 1][l] = _qb; } } while (0)

#define CBF(BUF, J) do { _Pragma("unroll") for (int _m = 0; _m < 4; ++_m) {     \
    float _qa = step(BUF[_m].x, BUF[_m].y, sms, gw, p);                         \
    float _qb = step(BUF[_m].z, BUF[_m].w, sms, gw, p);                         \
    orow2[ib0 + 4 * (J) + _m] = make_float2(_qa, _qb); } } while (0)

// ---------------------------------------------------------------------------
// Pass 1: one thread per (b, c); lanes = 64 consecutive b, c wave-uniform.
// Q buffered in LDS and written coalesced (store-transpose).
// ---------------------------------------------------------------------------

template<int T, int NC, int W>
__global__ __launch_bounds__(64, 1)
void hir_pass1(const float* __restrict__ inputs,
               const float* __restrict__ pINSC,  const float* __restrict__ pCOEFF,
               const float* __restrict__ pSQ,    const float* __restrict__ pSMSC,
               const float* __restrict__ pSUB,   const float* __restrict__ pCRAK,
               const float* __restrict__ pRecK,
               float* __restrict__ out, float4* __restrict__ st, int B)
{
    __shared__ float lds_q[64][65];        // [t_local][lane], +1 pad: bank-free
    const int l   = threadIdx.x;
    const int gid = blockIdx.x * 64 + l;
    const int b = gid % B;                 // consecutive lanes -> consecutive rows
    const int c = gid / B;                 // wave-uniform (B % 64 == 0)
    if (c >= NC) return;                   // never taken for the exact grid

    P p = make_params(pINSC, pCOEFF, pSQ, pSMSC, pSUB, pCRAK, pRecK);

    const float4* __restrict__ rp = (const float4*)(inputs + (size_t)b * (2 * T));
    float* __restrict__ orow = out + (size_t)b * T;

    constexpr int CH = T / NC;             // 64 steps
    const int i1 = (c * CH) >> 1;          // first main float4 index
    int i0 = i1 - (W >> 1);                // warm-up start (W/2 float4s)
    const bool exact = (i0 <= 0);
    if (i0 < 0) i0 = 0;

    float slo = 0.0f, shi = exact ? 0.0f : p.SMSC, gw = 0.0f;
    float4 B0[4], B1[4], B2[4], B3[4];

    // ---- Warm-up: pipelined batches (8 steps each), wave-uniform branch ----
    {
        const int nb = (i1 - i0) >> 2;     // in {0, 8, 16, 24, 32, 40}
        const float4* bp = rp + i0;
        if (exact) {
            PIPE4(nb, CBW);                // advances shi (true chain)
            slo = shi;
        } else {
            PIPE4(nb, CBD);                // dual bracket chains
        }
    }
    const bool merged = exact || ((shi - slo) <= MERGE_TOL);
    float sms = exact ? shi : (0.5f * (slo + shi));

    // ---- Main chunk: 8 batches, Q -> LDS (bank-conflict-free) ----
    {
        const float4* bp = rp + i1;
        PIPE4(8, CBM);
    }

    st[(size_t)c * B + b] = make_float4(sms, gw, merged ? 1.0f : 0.0f, 0.0f);

    // Q[b,0] from the final carry (jnp.roll wraparound), owned by chunk NC-1.
    float q0 = 0.0f;
    const bool hasq0 = (c == NC - 1);
    if (hasq0) {
        float4 f0 = rp[0];
        float ss = sms, gg = gw;
        q0 = step(f0.x, f0.y, ss, gg, p);
    }

    __syncthreads();                       // lds_q visible across the wave

    // ---- Store phase: coalesced columns. out[b0+j][t1+l] = lds_q[l][j] ----
    const int b0 = b - l;                  // wave base row (B % 64 == 0)
    const int t1 = c * CH;
    if (c == 0) {
        if (l > 0) {                       // lane 0 would write t=0 (owned by roll)
            for (int j = 0; j < 64; ++j)
                out[(size_t)(b0 + j) * T + l] = lds_q[l][j];
        }
    } else {
        for (int j = 0; j < 64; ++j)
            out[(size_t)(b0 + j) * T + t1 + l] = lds_q[l][j];
    }
    if (hasq0) orow[0] = q0;
}

// ---------------------------------------------------------------------------
// Fixup: thread per (b, c). Merged -> one coalesced st read, exit. Unmerged
// -> walk back to nearest merged predecessor m (chunk 0 is always exact =>
// merged), advance store-free through m+1..c-1, recompute chunk c exactly
// with direct out stores. Pipelined loads throughout. Same semantics as the
// sequential per-row fixup: merged states are accepted as-is.
// ---------------------------------------------------------------------------

template<int T, int NC>
__global__ __launch_bounds__(64)
void hir_fixup(const float* __restrict__ inputs,
               const float* __restrict__ pINSC,  const float* __restrict__ pCOEFF,
               const float* __restrict__ pSQ,    const float* __restrict__ pSMSC,
               const float* __restrict__ pSUB,   const float* __restrict__ pCRAK,
               const float* __restrict__ pRecK,
               float* __restrict__ out, const float4* __restrict__ st, int B)
{
    const int gid = blockIdx.x * 64 + threadIdx.x;
    const int b = gid % B;
    const int c = gid / B;
    if (c >= NC) return;

    float4 sc = st[(size_t)c * B + b];
    if (sc.z != 0.0f) return;              // merged -> nothing to fix

    P p = make_params(pINSC, pCOEFF, pSQ, pSMSC, pSUB, pCRAK, pRecK);
    constexpr int CH = T / NC;

    const float4* __restrict__ rp = (const float4*)(inputs + (size_t)b * (2 * T));
    float* __restrict__ orow = out + (size_t)b * T;
    float2* __restrict__ orow2 = (float2*)orow;

    // Walk back to nearest merged predecessor (c >= 1 here: chunk 0 merged).
    int m = c - 1;
    float4 sm = st[(size_t)m * B + b];
    while (sm.z == 0.0f) { --m; sm = st[(size_t)m * B + b]; }
    float sms = sm.x, gw = sm.y;

    float4 B0[4], B1[4], B2[4], B3[4];

    // Advance state through chunks m+1..c-1 (no stores), pipelined.
    {
        const int ia = ((m + 1) * CH) >> 1;
        const int ibx = (c * CH) >> 1;
        const int nb = (ibx - ia) >> 2;    // multiple of 8 (or 0)
        const float4* bp = rp + ia;
        float& shi = sms;                  // CBW advances "shi"
        PIPE4(nb, CBW);
    }

    // Recompute chunk c exactly, with stores, pipelined.
    {
        const int ib0 = (c * CH) >> 1;     // float2 output base index
        const float4* bp = rp + ib0;
        PIPE4(8, CBF);
    }

    if (c == NC - 1) {                     // rewrite the t=0 wraparound output
        float4 f0 = rp[0];
        float ss = sms, gg = gw;
        orow[0] = step(f0.x, f0.y, ss, gg, p);
    }
}

// Fallback: monolithic sequential (odd shapes / tiny workspace).
template<int T>
__global__ __launch_bounds__(64, 1)
void hir_scan_kernel(const float* __restrict__ inputs,
                     const float* __restrict__ pINSC,  const float* __restrict__ pCOEFF,
                     const float* __restrict__ pSQ,    const float* __restrict__ pSMSC,
                     const float* __restrict__ pSUB,   const float* __restrict__ pCRAK,
                     const float* __restrict__ pRecK,
                     float* __restrict__ out, int B)
{
    int b = blockIdx.x * blockDim.x + threadIdx.x;
    if (b >= B) return;
    P p = make_params(pINSC, pCOEFF, pSQ, pSMSC, pSUB, pCRAK, pRecK);
    const float4* __restrict__ rp = (const float4*)(inputs + (size_t)b * (2 * T));
    float* __restrict__ orow = out + (size_t)b * T;
    float sms = 0.0f, gw = 0.0f;
    float4 cur = rp[0];
    const float P0 = cur.x, E0 = cur.y;
    constexpr int NI = T / 2;
    for (int i = 0; i < NI; ++i) {
        int ni = (i + 1 < NI) ? (i + 1) : i;
        float4 nxt = rp[ni];
        float qa = step(cur.x, cur.y, sms, gw, p);
        float qb = step(cur.z, cur.w, sms, gw, p);
        if (i == 0) { orow[1] = qb; }
        else        { ((float2*)orow)[i] = make_float2(qa, qb); }
        cur = nxt;
    }
    float ss = sms, gg = gw;
    orow[0] = step(P0, E0, ss, gg, p);
}

extern "C" void kernel_launch(void* const* d_in, const int* in_sizes, int n_in,
                              void* d_out, int out_size, void* d_ws, size_t ws_size,
                              hipStream_t stream) {
    (void)n_in; (void)out_size;
    constexpr int T  = 1024;
    constexpr int NC = 16;    // chunks (CH=64)
    constexpr int W  = 320;   // warm-up: gap ~250*e^(-.0201*320) ~ 0.4 < 0.75
    const float* inputs = (const float*)d_in[0];
    const float* INSC   = (const float*)d_in[1];
    const float* COEFF  = (const float*)d_in[2];
    const float* SQ     = (const float*)d_in[3];
    const float* SMSC   = (const float*)d_in[4];
    const float* SUB    = (const float*)d_in[5];
    const float* CRAK   = (const float*)d_in[6];
    const float* RecK   = (const float*)d_in[7];
    float* out = (float*)d_out;

    int B = in_sizes[0] / (2 * T);            // 4096 for the reference shape
    size_t stBytes = (size_t)B * NC * sizeof(float4);   // 1 MB

    if ((B % 64) == 0 && ws_size >= stBytes) {
        float4* st = (float4*)d_ws;
        long total = (long)B * NC;            // 65536 threads = 1024 waves
        int blocks = (int)((total + 63) / 64);
        hir_pass1<T, NC, W><<<dim3(blocks), dim3(64), 0, stream>>>(
            inputs, INSC, COEFF, SQ, SMSC, SUB, CRAK, RecK, out, st, B);
        hir_fixup<T, NC><<<dim3(blocks), dim3(64), 0, stream>>>(
            inputs, INSC, COEFF, SQ, SMSC, SUB, CRAK, RecK, out, st, B);
        return;
    }

    int blocks = (B + 63) / 64;
    hir_scan_kernel<T><<<dim3(blocks), dim3(64), 0, stream>>>(
        inputs, INSC, COEFF, SQ, SMSC, SUB, CRAK, RecK, out, B);
}